// Round 21
// baseline (254.707 us; speedup 1.0000x reference)
//
#include <hip/hip_runtime.h>
#include <hip/hip_bf16.h>
#include <type_traits>

// ---------------- types & helpers ----------------
typedef unsigned short u16;
typedef __attribute__((ext_vector_type(8))) short bf16x8;   // 8 bf16 in 4 VGPRs
typedef __attribute__((ext_vector_type(4))) float f32x4;

#define AS1 __attribute__((address_space(1)))
#define AS3 __attribute__((address_space(3)))

__device__ __forceinline__ u16 f2bf(float x) {
  unsigned u = __float_as_uint(x);
  u += 0x7fffu + ((u >> 16) & 1u);   // round-to-nearest-even
  return (u16)(u >> 16);
}

// B=4, T=2048, C=1024, H=16, D=64
#define TT 2048
#define CC 1024
#define HH 16
#define DD 64

// scale * log2(e), folded into Q at the QKV epilogue
#define SL2E 0.1803368801111137f

// ---------------- fp32 -> bf16 convert (x), vectorized 8/thread ----------------
__global__ __launch_bounds__(256) void conv_f2bf(const float* __restrict__ in,
                                                 u16* __restrict__ out) {
  int i = blockIdx.x * 256 + threadIdx.x;
  const float4* p = (const float4*)in;
  float4 f0 = p[i * 2];
  float4 f1 = p[i * 2 + 1];
  u16 vv[8] = {f2bf(f0.x), f2bf(f0.y), f2bf(f0.z), f2bf(f0.w),
               f2bf(f1.x), f2bf(f1.y), f2bf(f1.z), f2bf(f1.w)};
  ((uint4*)out)[i] = *(const uint4*)vv;
}

// ---------------- weight transpose+convert: wt[n][k] = bf(w[k][n]) ----------------
__global__ __launch_bounds__(256) void transw(const float* __restrict__ w0,
                                              const float* __restrict__ w1,
                                              const float* __restrict__ w2,
                                              const float* __restrict__ w3,
                                              u16* __restrict__ wt_all) {
  __shared__ __align__(16) u16 tile[32][33];
  const float* w = blockIdx.z == 0 ? w0 : blockIdx.z == 1 ? w1 : blockIdx.z == 2 ? w2 : w3;
  u16* wt = wt_all + (size_t)blockIdx.z * (CC * CC);
  int k0 = blockIdx.y * 32, n0 = blockIdx.x * 32;
  int tx = threadIdx.x, ty = threadIdx.y;
#pragma unroll
  for (int i = 0; i < 4; ++i) {
    int r = ty + i * 8;
    tile[r][tx] = f2bf(w[(size_t)(k0 + r) * CC + n0 + tx]);
  }
  __syncthreads();
#pragma unroll
  for (int i = 0; i < 4; ++i) {
    int r = ty + i * 8;
    wt[(size_t)(n0 + r) * CC + k0 + tx] = tile[tx][r];
  }
}

// ---------------- GEMM bodies, BK=64 (32 MFMA per barrier pair) ----------------
// LDS rows are 128B -> XOR-swizzled on 16B slots: phys = logical ^ (row&7),
// applied on BOTH the gload_lds SOURCE column and the fragment reads (G21).

// QKV GEMM: A = xb bf16, B = wt bf16 -> [B,H,T,D]; Q pre-scaled by SL2E.
__global__ __launch_bounds__(256) void gemm_qkv(const u16* __restrict__ Xb,
                                                const u16* __restrict__ wt_all,
                                                const float* __restrict__ bq,
                                                const float* __restrict__ bk,
                                                const float* __restrict__ bv,
                                                u16* __restrict__ Qb,
                                                u16* __restrict__ Kb,
                                                u16* __restrict__ Vb) {
  __shared__ __align__(16) u16 As[128 * 64];
  __shared__ __align__(16) u16 Bs[128 * 64];
  const int z = blockIdx.z;
  const u16* Bt = wt_all + (size_t)z * (CC * CC);
  const float* bias = z == 0 ? bq : z == 1 ? bk : bv;
  u16* dst = z == 0 ? Qb : z == 1 ? Kb : Vb;
  const float oscale = (z == 0) ? SL2E : 1.0f;

  const int tid = threadIdx.x;
  const int l = tid & 63, w = tid >> 6;
  const int m0 = blockIdx.y * 128, n0 = blockIdx.x * 128;
  const int mw = (w >> 1) * 64, nw = (w & 1) * 64;

  auto stage = [&](int kt) {
    int kk = kt * 64;
#pragma unroll
    for (int it = 0; it < 4; ++it) {
      int c = tid + it * 256;                 // 1024 chunks of 16B per tile
      int row = c >> 3, s = c & 7;
      int g = s ^ (row & 7);                  // inverse-swizzled source column
      __builtin_amdgcn_global_load_lds(
          (const AS1 void*)(Bt + (size_t)(n0 + row) * CC + kk + g * 8),
          (AS3 void*)(Bs + c * 8), 16, 0, 0);
      __builtin_amdgcn_global_load_lds(
          (const AS1 void*)(Xb + (size_t)(m0 + row) * CC + kk + g * 8),
          (AS3 void*)(As + c * 8), 16, 0, 0);
    }
  };

  f32x4 acc[4][4] = {};
  stage(0);
  const int KT = CC >> 6;                     // 16 K-steps
  for (int kt = 0; kt < KT; ++kt) {
    __syncthreads();
#pragma unroll
    for (int half = 0; half < 2; ++half) {
      bf16x8 a[4], b[4];
#pragma unroll
      for (int i = 0; i < 4; ++i) {
        int ra = mw + i * 16 + (l & 15);
        int sa = (half * 4 + (l >> 4)) ^ (ra & 7);
        a[i] = *(const bf16x8*)(As + ra * 64 + sa * 8);
        int rb = nw + i * 16 + (l & 15);
        int sb = (half * 4 + (l >> 4)) ^ (rb & 7);
        b[i] = *(const bf16x8*)(Bs + rb * 64 + sb * 8);
      }
#pragma unroll
      for (int i = 0; i < 4; ++i)
#pragma unroll
        for (int j = 0; j < 4; ++j)
          acc[i][j] = __builtin_amdgcn_mfma_f32_16x16x32_bf16(a[i], b[j], acc[i][j], 0, 0, 0);
    }
    __syncthreads();
    if (kt + 1 < KT) stage(kt + 1);
  }

#pragma unroll
  for (int i = 0; i < 4; ++i) {
    int rowb = m0 + mw + i * 16 + ((l >> 4) << 2);
#pragma unroll
    for (int j = 0; j < 4; ++j) {
      int col = n0 + nw + j * 16 + (l & 15);
      float bv_ = bias[col];
      int h = col >> 6, d = col & 63;
#pragma unroll
      for (int r = 0; r < 4; ++r) {
        int row = rowb + r;
        int bb = row >> 11, t = row & (TT - 1);
        dst[(((size_t)(bb * HH + h)) * TT + t) * DD + d] = f2bf((acc[i][j][r] + bv_) * oscale);
      }
    }
  }
}

// OUT GEMM: A = O in [B,H,T,D] bf16 (gathered), B = wo^T; fp32 out.
__global__ __launch_bounds__(256) void gemm_out(const u16* __restrict__ Oh,
                                                const u16* __restrict__ Bt,
                                                const float* __restrict__ bias,
                                                float* __restrict__ dst) {
  __shared__ __align__(16) u16 As[128 * 64];
  __shared__ __align__(16) u16 Bs[128 * 64];
  const int tid = threadIdx.x;
  const int l = tid & 63, w = tid >> 6;
  const int m0 = blockIdx.y * 128, n0 = blockIdx.x * 128;
  const int mw = (w >> 1) * 64, nw = (w & 1) * 64;

  auto stage = [&](int kt) {
    int kk = kt * 64;
#pragma unroll
    for (int it = 0; it < 4; ++it) {
      int c = tid + it * 256;
      int row = c >> 3, s = c & 7;
      int g = s ^ (row & 7);
      __builtin_amdgcn_global_load_lds(
          (const AS1 void*)(Bt + (size_t)(n0 + row) * CC + kk + g * 8),
          (AS3 void*)(Bs + c * 8), 16, 0, 0);
      // A gather from [B,H,T,D]: k = h*64+d; 8-chunks never cross head boundary
      int gr = m0 + row, gk = kk + g * 8;
      int bb = gr >> 11, t = gr & (TT - 1);
      int h = gk >> 6, d = gk & 63;
      __builtin_amdgcn_global_load_lds(
          (const AS1 void*)(Oh + (((size_t)(bb * HH + h)) * TT + t) * DD + d),
          (AS3 void*)(As + c * 8), 16, 0, 0);
    }
  };

  f32x4 acc[4][4] = {};
  stage(0);
  const int KT = CC >> 6;
  for (int kt = 0; kt < KT; ++kt) {
    __syncthreads();
#pragma unroll
    for (int half = 0; half < 2; ++half) {
      bf16x8 a[4], b[4];
#pragma unroll
      for (int i = 0; i < 4; ++i) {
        int ra = mw + i * 16 + (l & 15);
        int sa = (half * 4 + (l >> 4)) ^ (ra & 7);
        a[i] = *(const bf16x8*)(As + ra * 64 + sa * 8);
        int rb = nw + i * 16 + (l & 15);
        int sb = (half * 4 + (l >> 4)) ^ (rb & 7);
        b[i] = *(const bf16x8*)(Bs + rb * 64 + sb * 8);
      }
#pragma unroll
      for (int i = 0; i < 4; ++i)
#pragma unroll
        for (int j = 0; j < 4; ++j)
          acc[i][j] = __builtin_amdgcn_mfma_f32_16x16x32_bf16(a[i], b[j], acc[i][j], 0, 0, 0);
    }
    __syncthreads();
    if (kt + 1 < KT) stage(kt + 1);
  }

#pragma unroll
  for (int i = 0; i < 4; ++i) {
    int rowb = m0 + mw + i * 16 + ((l >> 4) << 2);
#pragma unroll
    for (int j = 0; j < 4; ++j) {
      int col = n0 + nw + j * 16 + (l & 15);
      float bv_ = bias[col];
#pragma unroll
      for (int r = 0; r < 4; ++r)
        dst[(size_t)(rowb + r) * CC + col] = acc[i][j][r] + bv_;
    }
  }
}

// ---------------- causal flash attention v13 ----------------
// 8 waves x 32 q-rows = 256-row q-tiles (K/V staging+barriers per q-row halved
// again vs v12b). Single-buffer 48KB LDS; grid (bh=64, qt=8) = 512 blocks = 2/CU.
// qt paired heavy+light (j<4 ? j : 11-j) so per-CU pair sums are equal (36).
// Body identical to r19/r20-refchecked v12; (512,4) = no-spill bound (r11+).
__global__ __launch_bounds__(512, 4) void attn_kernel(u16* __restrict__ Q,
                                                      const u16* __restrict__ K,
                                                      const u16* __restrict__ V) {
  __shared__ __align__(16) u16 Ks[64 * 64];      // [key][d], swizzled
  __shared__ __align__(16) u16 Vt[64 * 64];      // [d][key], swizzled
  __shared__ __align__(16) u16 Ps[8][32 * 64];   // per-wave P (32 rows), swizzled

  const int tid = threadIdx.x;
  const int l = tid & 63, w = tid >> 6;          // 8 waves
  const int bh = blockIdx.x;                      // 0..63  (XCD = bh%8)
  const int j = blockIdx.y;                       // 0..7
  const int qt = (j < 4) ? j : 11 - j;            // heavy+light pairing
  const size_t base = (size_t)bh * TT * DD;
  const int kp = tid & 31;                        // V-stage: key pair
  const int dgr = tid >> 5;                       // V-stage: d-group of 4 (0..15)

  const int q0 = TT - 256 - qt * 256;             // qt=0 -> heaviest (nch=32)
  const int nch = (q0 >> 6) + 4;                  // >= 4
  const int wrow0 = q0 + w * 32;

  bf16x8 vones;
#pragma unroll
  for (int jj = 0; jj < 8; ++jj) vones[jj] = (short)0x3F80;

  auto stageK = [&](int k0) {
    int c = tid;                                  // 512 chunks of 16B
    int row = c >> 3, s = c & 7;
    int g = s ^ (row & 7);
    __builtin_amdgcn_global_load_lds(
        (const AS1 void*)(K + base + (size_t)(k0 + row) * DD + g * 8),
        (AS3 void*)(Ks + c * 8), 16, 0, 0);
  };
  auto loadV = [&](int k0, uint2& a0, uint2& a1) {
    const u16* vp0 = V + base + (size_t)(k0 + 2 * kp) * DD + dgr * 4;
    a0 = *(const uint2*)vp0;
    a1 = *(const uint2*)(vp0 + DD);
  };
  auto writeV = [&](uint2 a0, uint2 a1) {
    u16 v0[4], v1[4];
    *(uint2*)v0 = a0; *(uint2*)v1 = a1;
#pragma unroll
    for (int jj = 0; jj < 4; ++jj) {
      int d = dgr * 4 + jj;
      unsigned pk = (unsigned)v0[jj] | ((unsigned)v1[jj] << 16);
      int addr = d * 64 + (((kp >> 2) ^ (d & 7)) << 3) + ((kp & 3) << 1);
      *(unsigned*)(Vt + addr) = pk;
    }
  };

  // Q fragments: 2 row-tiles per wave (rows wrow0..wrow0+31), Q pre-scaled
  bf16x8 qa[2][2];
#pragma unroll
  for (int mt = 0; mt < 2; ++mt) {
    const u16* qp = Q + base + (size_t)(wrow0 + mt * 16 + (l & 15)) * DD + (l >> 4) * 8;
    qa[mt][0] = *(const bf16x8*)(qp);
    qa[mt][1] = *(const bf16x8*)(qp + 32);
  }

  f32x4 oacc[2][5] = {};                          // [mt][0..3]=O, [mt][4]=rowsum

  // body: all LDS addresses loop-invariant (single buffer); masked compile-time
  auto body = [&](auto maskedC, int k0) {
    constexpr bool masked = decltype(maskedC)::value;
    bool act0 = true, act1 = true;
    if (masked) {
      act1 = (k0 <= wrow0 + 31);
      act0 = (k0 <= wrow0 + 15);
      if (!act1) return;                          // act0 implies act1
    }
    const bool need_mask = masked && (k0 + 63 > wrow0);

    // --- S = Q K^T (up to 32 q-rows x 64 k) ---
    f32x4 sa[2][4];
#pragma unroll
    for (int nt = 0; nt < 4; ++nt) {
      int krow = nt * 16 + (l & 15);
      int rb = krow & 7;
      bf16x8 kb0 = *(const bf16x8*)(Ks + krow * 64 + (((l >> 4) ^ rb) << 3));
      bf16x8 kb1 = *(const bf16x8*)(Ks + krow * 64 + ((((l >> 4) + 4) ^ rb) << 3));
#pragma unroll
      for (int mt = 0; mt < 2; ++mt) {
        if (!masked || (mt ? act1 : act0)) {
          f32x4 zz = {};
          zz = __builtin_amdgcn_mfma_f32_16x16x32_bf16(qa[mt][0], kb0, zz, 0, 0, 0);
          zz = __builtin_amdgcn_mfma_f32_16x16x32_bf16(qa[mt][1], kb1, zz, 0, 0, 0);
          sa[mt][nt] = zz;
        }
      }
    }

    // --- softmax numerators: p = exp2(s); trunc bf16 store ---
#pragma unroll
    for (int mt = 0; mt < 2; ++mt) {
      if (!masked || (mt ? act1 : act0)) {
#pragma unroll
        for (int r = 0; r < 4; ++r) {
          int lrow = mt * 16 + ((l >> 4) << 2) + r;   // 0..31
          int row = wrow0 + lrow;
#pragma unroll
          for (int nt = 0; nt < 4; ++nt) {
            float p = exp2f(sa[mt][nt][r]);
            if (masked) {
              if (need_mask) {
                int col = k0 + nt * 16 + (l & 15);
                if (col > row) p = 0.f;
              }
            }
            int slot = ((2 * nt + ((l & 15) >> 3)) & 7) ^ (lrow & 7);
            Ps[w][lrow * 64 + (slot << 3) + (l & 7)] =
                (u16)(__float_as_uint(p) >> 16);      // trunc; cancels num/denom
          }
        }
      }
    }

    // --- O += P @ V; dt=4 uses reg-ones -> rowsum ---
    bf16x8 pa[2][2];
#pragma unroll
    for (int mt = 0; mt < 2; ++mt) {
      if (!masked || (mt ? act1 : act0)) {
        int arow = mt * 16 + (l & 15), ab = arow & 7;
        pa[mt][0] = *(const bf16x8*)(&Ps[w][arow * 64 + (((l >> 4) ^ ab) << 3)]);
        pa[mt][1] = *(const bf16x8*)(&Ps[w][arow * 64 + ((((l >> 4) + 4) ^ ab) << 3)]);
      }
    }
#pragma unroll
    for (int dt = 0; dt < 5; ++dt) {
      bf16x8 vb0, vb1;
      if (dt < 4) {
        int vrow = dt * 16 + (l & 15), vb = vrow & 7;
        vb0 = *(const bf16x8*)(Vt + vrow * 64 + (((l >> 4) ^ vb) << 3));
        vb1 = *(const bf16x8*)(Vt + vrow * 64 + ((((l >> 4) + 4) ^ vb) << 3));
      } else {
        vb0 = vones; vb1 = vones;
      }
#pragma unroll
      for (int mt = 0; mt < 2; ++mt) {
        if (!masked || (mt ? act1 : act0)) {
          oacc[mt][dt] = __builtin_amdgcn_mfma_f32_16x16x32_bf16(pa[mt][0], vb0, oacc[mt][dt], 0, 0, 0);
          oacc[mt][dt] = __builtin_amdgcn_mfma_f32_16x16x32_bf16(pa[mt][1], vb1, oacc[mt][dt], 0, 0, 0);
        }
      }
    }
  };

  constexpr std::false_type noMask{};
  constexpr std::true_type  doMask{};

  // prologue: stage chunk 0
  {
    uint2 a0, a1;
    stageK(0);
    loadV(0, a0, a1);
    writeV(a0, a1);
    __syncthreads();
  }

  // unmasked chunks 0..nch-5 (k0+63 < q0 for all of them)
  const int mainN = nch - 4;
  for (int ch = 0; ch < mainN; ++ch) {
    uint2 na0, na1;
    loadV((ch + 1) * 64, na0, na1);               // issue EARLY (regs, not LDS)
    body(noMask, ch * 64);
    __syncthreads();                              // Ks/Vt free
    stageK((ch + 1) * 64);
    writeV(na0, na1);
    __syncthreads();                              // next chunk published
  }
  // masked diagonal chunks nch-4..nch-1
  for (int ch = mainN; ch < nch; ++ch) {
    const bool hn = (ch + 1 < nch);
    uint2 na0, na1;
    if (hn) loadV((ch + 1) * 64, na0, na1);
    body(doMask, ch * 64);
    __syncthreads();
    if (hn) {
      stageK((ch + 1) * 64);
      writeV(na0, na1);
      __syncthreads();
    }
  }

  // --- normalize + write O over Q (rows owned by this block only) ---
#pragma unroll
  for (int mt = 0; mt < 2; ++mt) {
#pragma unroll
    for (int r = 0; r < 4; ++r) {
      float inv = 1.f / oacc[mt][4][r];
      int t = wrow0 + mt * 16 + ((l >> 4) << 2) + r;
#pragma unroll
      for (int dt = 0; dt < 4; ++dt)
        Q[base + (size_t)t * DD + dt * 16 + (l & 15)] = f2bf(oacc[mt][dt][r] * inv);
    }
  }
}

// ---------------- launcher ----------------
extern "C" void kernel_launch(void* const* d_in, const int* in_sizes, int n_in,
                              void* d_out, int out_size, void* d_ws, size_t ws_size,
                              hipStream_t stream) {
  const float* x  = (const float*)d_in[0];
  const float* wq = (const float*)d_in[1];
  const float* bq = (const float*)d_in[2];
  const float* wk = (const float*)d_in[3];
  const float* bk = (const float*)d_in[4];
  const float* wv = (const float*)d_in[5];
  const float* bv = (const float*)d_in[6];
  const float* wo = (const float*)d_in[7];
  const float* bo = (const float*)d_in[8];

  const size_t M   = 4 * (size_t)TT;           // 8192
  const size_t wtB = (size_t)CC * CC * 2;      // 2 MB per transposed weight
  const size_t qB  = M * CC * 2;               // 16.78 MB per Q/K/V tensor
  const size_t need = 4 * wtB + 3 * qB;        // 58,720,256 B

  if (ws_size < need) return;

  char* ws = (char*)d_ws;
  u16* wt_all = (u16*)ws;
  u16* Qb     = (u16*)(ws + 4 * wtB);
  u16* Kb     = Qb + M * CC;
  u16* Vb     = Kb + M * CC;
  // xb (bf16 x) lives in d_out's first half; gemm_out fully overwrites d_out.
  u16* xb     = (u16*)d_out;

  // 1) x -> bf16 into d_out scratch
  conv_f2bf<<<dim3(4096), dim3(256), 0, stream>>>(x, xb);

  // 2) transpose-convert the 4 weights
  transw<<<dim3(32, 32, 4), dim3(32, 8), 0, stream>>>(wq, wk, wv, wo, wt_all);

  // 3) QKV projections (BK=64, swizzled LDS) -> [B,H,T,D]; Q pre-scaled by SL2E
  gemm_qkv<<<dim3(CC / 128, M / 128, 3), dim3(256), 0, stream>>>(
      xb, wt_all, bq, bk, bv, Qb, Kb, Vb);

  // 4) causal attention v13 (256-row tiles, 8 waves x 32 rows, paired qt)
  attn_kernel<<<dim3(4 * HH, 8), dim3(512), 0, stream>>>(Qb, Kb, Vb);

  // 5) output projection (BK=64, swizzled LDS) -> d_out (FP32)
  gemm_out<<<dim3(CC / 128, M / 128, 1), dim3(256), 0, stream>>>(
      Qb, wt_all + 3 * (size_t)CC * CC, bo, (float*)d_out);
}

// Round 22
// 177.104 us; speedup vs baseline: 1.4382x; 1.4382x over previous
//
#include <hip/hip_runtime.h>
#include <hip/hip_bf16.h>
#include <type_traits>

// ---------------- types & helpers ----------------
typedef unsigned short u16;
typedef __attribute__((ext_vector_type(8))) short bf16x8;   // 8 bf16 in 4 VGPRs
typedef __attribute__((ext_vector_type(4))) float f32x4;

#define AS1 __attribute__((address_space(1)))
#define AS3 __attribute__((address_space(3)))

__device__ __forceinline__ u16 f2bf(float x) {
  unsigned u = __float_as_uint(x);
  u += 0x7fffu + ((u >> 16) & 1u);   // round-to-nearest-even
  return (u16)(u >> 16);
}

// B=4, T=2048, C=1024, H=16, D=64
#define TT 2048
#define CC 1024
#define HH 16
#define DD 64

// scale * log2(e), folded into Q at the QKV epilogue
#define SL2E 0.1803368801111137f

// ---------------- fp32 -> bf16 convert (x), vectorized 8/thread ----------------
__global__ __launch_bounds__(256) void conv_f2bf(const float* __restrict__ in,
                                                 u16* __restrict__ out) {
  int i = blockIdx.x * 256 + threadIdx.x;
  const float4* p = (const float4*)in;
  float4 f0 = p[i * 2];
  float4 f1 = p[i * 2 + 1];
  u16 vv[8] = {f2bf(f0.x), f2bf(f0.y), f2bf(f0.z), f2bf(f0.w),
               f2bf(f1.x), f2bf(f1.y), f2bf(f1.z), f2bf(f1.w)};
  ((uint4*)out)[i] = *(const uint4*)vv;
}

// ---------------- weight transpose+convert: wt[n][k] = bf(w[k][n]) ----------------
__global__ __launch_bounds__(256) void transw(const float* __restrict__ w0,
                                              const float* __restrict__ w1,
                                              const float* __restrict__ w2,
                                              const float* __restrict__ w3,
                                              u16* __restrict__ wt_all) {
  __shared__ __align__(16) u16 tile[32][33];
  const float* w = blockIdx.z == 0 ? w0 : blockIdx.z == 1 ? w1 : blockIdx.z == 2 ? w2 : w3;
  u16* wt = wt_all + (size_t)blockIdx.z * (CC * CC);
  int k0 = blockIdx.y * 32, n0 = blockIdx.x * 32;
  int tx = threadIdx.x, ty = threadIdx.y;
#pragma unroll
  for (int i = 0; i < 4; ++i) {
    int r = ty + i * 8;
    tile[r][tx] = f2bf(w[(size_t)(k0 + r) * CC + n0 + tx]);
  }
  __syncthreads();
#pragma unroll
  for (int i = 0; i < 4; ++i) {
    int r = ty + i * 8;
    wt[(size_t)(n0 + r) * CC + k0 + tx] = tile[tx][r];
  }
}

// ---------------- GEMM bodies, BK=64 (32 MFMA per barrier pair) ----------------
// LDS rows are 128B -> XOR-swizzled on 16B slots: phys = logical ^ (row&7),
// applied on BOTH the gload_lds SOURCE column and the fragment reads (G21).

// QKV GEMM: A = xb bf16, B = wt bf16 -> [B,H,T,D]; Q pre-scaled by SL2E.
__global__ __launch_bounds__(256) void gemm_qkv(const u16* __restrict__ Xb,
                                                const u16* __restrict__ wt_all,
                                                const float* __restrict__ bq,
                                                const float* __restrict__ bk,
                                                const float* __restrict__ bv,
                                                u16* __restrict__ Qb,
                                                u16* __restrict__ Kb,
                                                u16* __restrict__ Vb) {
  __shared__ __align__(16) u16 As[128 * 64];
  __shared__ __align__(16) u16 Bs[128 * 64];
  const int z = blockIdx.z;
  const u16* Bt = wt_all + (size_t)z * (CC * CC);
  const float* bias = z == 0 ? bq : z == 1 ? bk : bv;
  u16* dst = z == 0 ? Qb : z == 1 ? Kb : Vb;
  const float oscale = (z == 0) ? SL2E : 1.0f;

  const int tid = threadIdx.x;
  const int l = tid & 63, w = tid >> 6;
  const int m0 = blockIdx.y * 128, n0 = blockIdx.x * 128;
  const int mw = (w >> 1) * 64, nw = (w & 1) * 64;

  auto stage = [&](int kt) {
    int kk = kt * 64;
#pragma unroll
    for (int it = 0; it < 4; ++it) {
      int c = tid + it * 256;                 // 1024 chunks of 16B per tile
      int row = c >> 3, s = c & 7;
      int g = s ^ (row & 7);                  // inverse-swizzled source column
      __builtin_amdgcn_global_load_lds(
          (const AS1 void*)(Bt + (size_t)(n0 + row) * CC + kk + g * 8),
          (AS3 void*)(Bs + c * 8), 16, 0, 0);
      __builtin_amdgcn_global_load_lds(
          (const AS1 void*)(Xb + (size_t)(m0 + row) * CC + kk + g * 8),
          (AS3 void*)(As + c * 8), 16, 0, 0);
    }
  };

  f32x4 acc[4][4] = {};
  stage(0);
  const int KT = CC >> 6;                     // 16 K-steps
  for (int kt = 0; kt < KT; ++kt) {
    __syncthreads();
#pragma unroll
    for (int half = 0; half < 2; ++half) {
      bf16x8 a[4], b[4];
#pragma unroll
      for (int i = 0; i < 4; ++i) {
        int ra = mw + i * 16 + (l & 15);
        int sa = (half * 4 + (l >> 4)) ^ (ra & 7);
        a[i] = *(const bf16x8*)(As + ra * 64 + sa * 8);
        int rb = nw + i * 16 + (l & 15);
        int sb = (half * 4 + (l >> 4)) ^ (rb & 7);
        b[i] = *(const bf16x8*)(Bs + rb * 64 + sb * 8);
      }
#pragma unroll
      for (int i = 0; i < 4; ++i)
#pragma unroll
        for (int j = 0; j < 4; ++j)
          acc[i][j] = __builtin_amdgcn_mfma_f32_16x16x32_bf16(a[i], b[j], acc[i][j], 0, 0, 0);
    }
    __syncthreads();
    if (kt + 1 < KT) stage(kt + 1);
  }

#pragma unroll
  for (int i = 0; i < 4; ++i) {
    int rowb = m0 + mw + i * 16 + ((l >> 4) << 2);
#pragma unroll
    for (int j = 0; j < 4; ++j) {
      int col = n0 + nw + j * 16 + (l & 15);
      float bv_ = bias[col];
      int h = col >> 6, d = col & 63;
#pragma unroll
      for (int r = 0; r < 4; ++r) {
        int row = rowb + r;
        int bb = row >> 11, t = row & (TT - 1);
        dst[(((size_t)(bb * HH + h)) * TT + t) * DD + d] = f2bf((acc[i][j][r] + bv_) * oscale);
      }
    }
  }
}

// OUT GEMM: A = O in [B,H,T,D] bf16 (gathered), B = wo^T; fp32 out.
__global__ __launch_bounds__(256) void gemm_out(const u16* __restrict__ Oh,
                                                const u16* __restrict__ Bt,
                                                const float* __restrict__ bias,
                                                float* __restrict__ dst) {
  __shared__ __align__(16) u16 As[128 * 64];
  __shared__ __align__(16) u16 Bs[128 * 64];
  const int tid = threadIdx.x;
  const int l = tid & 63, w = tid >> 6;
  const int m0 = blockIdx.y * 128, n0 = blockIdx.x * 128;
  const int mw = (w >> 1) * 64, nw = (w & 1) * 64;

  auto stage = [&](int kt) {
    int kk = kt * 64;
#pragma unroll
    for (int it = 0; it < 4; ++it) {
      int c = tid + it * 256;
      int row = c >> 3, s = c & 7;
      int g = s ^ (row & 7);
      __builtin_amdgcn_global_load_lds(
          (const AS1 void*)(Bt + (size_t)(n0 + row) * CC + kk + g * 8),
          (AS3 void*)(Bs + c * 8), 16, 0, 0);
      // A gather from [B,H,T,D]: k = h*64+d; 8-chunks never cross head boundary
      int gr = m0 + row, gk = kk + g * 8;
      int bb = gr >> 11, t = gr & (TT - 1);
      int h = gk >> 6, d = gk & 63;
      __builtin_amdgcn_global_load_lds(
          (const AS1 void*)(Oh + (((size_t)(bb * HH + h)) * TT + t) * DD + d),
          (AS3 void*)(As + c * 8), 16, 0, 0);
    }
  };

  f32x4 acc[4][4] = {};
  stage(0);
  const int KT = CC >> 6;
  for (int kt = 0; kt < KT; ++kt) {
    __syncthreads();
#pragma unroll
    for (int half = 0; half < 2; ++half) {
      bf16x8 a[4], b[4];
#pragma unroll
      for (int i = 0; i < 4; ++i) {
        int ra = mw + i * 16 + (l & 15);
        int sa = (half * 4 + (l >> 4)) ^ (ra & 7);
        a[i] = *(const bf16x8*)(As + ra * 64 + sa * 8);
        int rb = nw + i * 16 + (l & 15);
        int sb = (half * 4 + (l >> 4)) ^ (rb & 7);
        b[i] = *(const bf16x8*)(Bs + rb * 64 + sb * 8);
      }
#pragma unroll
      for (int i = 0; i < 4; ++i)
#pragma unroll
        for (int j = 0; j < 4; ++j)
          acc[i][j] = __builtin_amdgcn_mfma_f32_16x16x32_bf16(a[i], b[j], acc[i][j], 0, 0, 0);
    }
    __syncthreads();
    if (kt + 1 < KT) stage(kt + 1);
  }

#pragma unroll
  for (int i = 0; i < 4; ++i) {
    int rowb = m0 + mw + i * 16 + ((l >> 4) << 2);
#pragma unroll
    for (int j = 0; j < 4; ++j) {
      int col = n0 + nw + j * 16 + (l & 15);
      float bv_ = bias[col];
#pragma unroll
      for (int r = 0; r < 4; ++r)
        dst[(size_t)(rowb + r) * CC + col] = acc[i][j][r] + bv_;
    }
  }
}

// ---------------- causal flash attention v12b (round-20 best: 79.5 us) ----------------
// 32 rows/wave x 4 waves, single-buffer 32KB LDS (5 blocks/CU), heavy-first grid,
// XCD=bh%8, trunc Ps store, reg-ones rowsum, (256,3) = verified no-spill bound.
__global__ __launch_bounds__(256, 3) void attn_kernel(u16* __restrict__ Q,
                                                      const u16* __restrict__ K,
                                                      const u16* __restrict__ V) {
  __shared__ __align__(16) u16 Ks[64 * 64];      // [key][d], swizzled
  __shared__ __align__(16) u16 Vt[64 * 64];      // [d][key], swizzled
  __shared__ __align__(16) u16 Ps[4][32 * 64];   // per-wave P (32 rows), swizzled

  const int tid = threadIdx.x;
  const int l = tid & 63, w = tid >> 6;          // 4 waves
  const int bh = blockIdx.x;                      // 0..63  (XCD = bh%8)
  const int qt = blockIdx.y;                      // 0..15, heavy-first
  const size_t base = (size_t)bh * TT * DD;
  const int kp = tid & 31;                        // V-stage: key pair
  const int dgr = tid >> 5;                       // V-stage: d-group of 8 (0..7)

  const int q0 = TT - 128 - qt * 128;             // qt=0 -> heaviest (nch=32)
  const int nch = (q0 >> 6) + 2;                  // >= 4
  const int wrow0 = q0 + w * 32;

  bf16x8 vones;
#pragma unroll
  for (int j = 0; j < 8; ++j) vones[j] = (short)0x3F80;

  auto stageK = [&](int k0) {
#pragma unroll
    for (int it = 0; it < 2; ++it) {
      int c = tid + it * 256;                     // 512 chunks of 16B
      int row = c >> 3, s = c & 7;
      int g = s ^ (row & 7);
      __builtin_amdgcn_global_load_lds(
          (const AS1 void*)(K + base + (size_t)(k0 + row) * DD + g * 8),
          (AS3 void*)(Ks + c * 8), 16, 0, 0);
    }
  };
  auto loadV = [&](int k0, uint4& a0, uint4& a1) {
    const u16* vp = V + base + (size_t)(k0 + 2 * kp) * DD + dgr * 8;
    a0 = *(const uint4*)vp;
    a1 = *(const uint4*)(vp + DD);
  };
  auto writeV = [&](uint4 a0, uint4 a1) {
    u16 v0[8], v1[8];
    *(uint4*)v0 = a0; *(uint4*)v1 = a1;
#pragma unroll
    for (int j = 0; j < 8; ++j) {
      int d = dgr * 8 + j;
      unsigned pk = (unsigned)v0[j] | ((unsigned)v1[j] << 16);
      int addr = d * 64 + (((kp >> 2) ^ (d & 7)) << 3) + ((kp & 3) << 1);
      *(unsigned*)(Vt + addr) = pk;
    }
  };

  // Q fragments: 2 row-tiles per wave (rows wrow0..wrow0+31), Q pre-scaled
  bf16x8 qa[2][2];
#pragma unroll
  for (int mt = 0; mt < 2; ++mt) {
    const u16* qp = Q + base + (size_t)(wrow0 + mt * 16 + (l & 15)) * DD + (l >> 4) * 8;
    qa[mt][0] = *(const bf16x8*)(qp);
    qa[mt][1] = *(const bf16x8*)(qp + 32);
  }

  f32x4 oacc[2][5] = {};                          // [mt][0..3]=O, [mt][4]=rowsum

  // body: all LDS addresses loop-invariant (single buffer); masked compile-time
  auto body = [&](auto maskedC, int k0) {
    constexpr bool masked = decltype(maskedC)::value;
    bool act0 = true, act1 = true;
    if (masked) {
      act1 = (k0 <= wrow0 + 31);
      act0 = (k0 <= wrow0 + 15);
      if (!act1) return;                          // act0 implies act1
    }
    const bool need_mask = masked && (k0 + 63 > wrow0);

    // --- S = Q K^T (up to 32 q-rows x 64 k) ---
    f32x4 sa[2][4];
#pragma unroll
    for (int nt = 0; nt < 4; ++nt) {
      int krow = nt * 16 + (l & 15);
      int rb = krow & 7;
      bf16x8 kb0 = *(const bf16x8*)(Ks + krow * 64 + (((l >> 4) ^ rb) << 3));
      bf16x8 kb1 = *(const bf16x8*)(Ks + krow * 64 + ((((l >> 4) + 4) ^ rb) << 3));
#pragma unroll
      for (int mt = 0; mt < 2; ++mt) {
        if (!masked || (mt ? act1 : act0)) {
          f32x4 zz = {};
          zz = __builtin_amdgcn_mfma_f32_16x16x32_bf16(qa[mt][0], kb0, zz, 0, 0, 0);
          zz = __builtin_amdgcn_mfma_f32_16x16x32_bf16(qa[mt][1], kb1, zz, 0, 0, 0);
          sa[mt][nt] = zz;
        }
      }
    }

    // --- softmax numerators: p = exp2(s); trunc bf16 store ---
#pragma unroll
    for (int mt = 0; mt < 2; ++mt) {
      if (!masked || (mt ? act1 : act0)) {
#pragma unroll
        for (int r = 0; r < 4; ++r) {
          int lrow = mt * 16 + ((l >> 4) << 2) + r;   // 0..31
          int row = wrow0 + lrow;
#pragma unroll
          for (int nt = 0; nt < 4; ++nt) {
            float p = exp2f(sa[mt][nt][r]);
            if (masked) {
              if (need_mask) {
                int col = k0 + nt * 16 + (l & 15);
                if (col > row) p = 0.f;
              }
            }
            int slot = ((2 * nt + ((l & 15) >> 3)) & 7) ^ (lrow & 7);
            Ps[w][lrow * 64 + (slot << 3) + (l & 7)] =
                (u16)(__float_as_uint(p) >> 16);      // trunc; cancels num/denom
          }
        }
      }
    }

    // --- O += P @ V; dt=4 uses reg-ones -> rowsum ---
    bf16x8 pa[2][2];
#pragma unroll
    for (int mt = 0; mt < 2; ++mt) {
      if (!masked || (mt ? act1 : act0)) {
        int arow = mt * 16 + (l & 15), ab = arow & 7;
        pa[mt][0] = *(const bf16x8*)(&Ps[w][arow * 64 + (((l >> 4) ^ ab) << 3)]);
        pa[mt][1] = *(const bf16x8*)(&Ps[w][arow * 64 + ((((l >> 4) + 4) ^ ab) << 3)]);
      }
    }
#pragma unroll
    for (int dt = 0; dt < 5; ++dt) {
      bf16x8 vb0, vb1;
      if (dt < 4) {
        int vrow = dt * 16 + (l & 15), vb = vrow & 7;
        vb0 = *(const bf16x8*)(Vt + vrow * 64 + (((l >> 4) ^ vb) << 3));
        vb1 = *(const bf16x8*)(Vt + vrow * 64 + ((((l >> 4) + 4) ^ vb) << 3));
      } else {
        vb0 = vones; vb1 = vones;
      }
#pragma unroll
      for (int mt = 0; mt < 2; ++mt) {
        if (!masked || (mt ? act1 : act0)) {
          oacc[mt][dt] = __builtin_amdgcn_mfma_f32_16x16x32_bf16(pa[mt][0], vb0, oacc[mt][dt], 0, 0, 0);
          oacc[mt][dt] = __builtin_amdgcn_mfma_f32_16x16x32_bf16(pa[mt][1], vb1, oacc[mt][dt], 0, 0, 0);
        }
      }
    }
  };

  constexpr std::false_type noMask{};
  constexpr std::true_type  doMask{};

  // prologue: stage chunk 0
  {
    uint4 a0, a1;
    stageK(0);
    loadV(0, a0, a1);
    writeV(a0, a1);
    __syncthreads();
  }

  // unmasked chunks 0..nch-3
  for (int ch = 0; ch < nch - 2; ++ch) {
    uint4 na0, na1;
    loadV((ch + 1) * 64, na0, na1);               // issue EARLY (regs, not LDS)
    body(noMask, ch * 64);
    __syncthreads();                              // Ks/Vt free
    stageK((ch + 1) * 64);
    writeV(na0, na1);
    __syncthreads();                              // next chunk published
  }
  // masked chunk nch-2 (stages nch-1 after), then masked chunk nch-1
  {
    uint4 na0, na1;
    loadV((nch - 1) * 64, na0, na1);
    body(doMask, (nch - 2) * 64);
    __syncthreads();
    stageK((nch - 1) * 64);
    writeV(na0, na1);
    __syncthreads();
  }
  body(doMask, (nch - 1) * 64);

  // --- normalize + write O over Q (rows owned by this block only) ---
#pragma unroll
  for (int mt = 0; mt < 2; ++mt) {
#pragma unroll
    for (int r = 0; r < 4; ++r) {
      float inv = 1.f / oacc[mt][4][r];
      int t = wrow0 + mt * 16 + ((l >> 4) << 2) + r;
#pragma unroll
      for (int dt = 0; dt < 4; ++dt)
        Q[base + (size_t)t * DD + dt * 16 + (l & 15)] = f2bf(oacc[mt][dt][r] * inv);
    }
  }
}

// ---------------- launcher ----------------
extern "C" void kernel_launch(void* const* d_in, const int* in_sizes, int n_in,
                              void* d_out, int out_size, void* d_ws, size_t ws_size,
                              hipStream_t stream) {
  const float* x  = (const float*)d_in[0];
  const float* wq = (const float*)d_in[1];
  const float* bq = (const float*)d_in[2];
  const float* wk = (const float*)d_in[3];
  const float* bk = (const float*)d_in[4];
  const float* wv = (const float*)d_in[5];
  const float* bv = (const float*)d_in[6];
  const float* wo = (const float*)d_in[7];
  const float* bo = (const float*)d_in[8];

  const size_t M   = 4 * (size_t)TT;           // 8192
  const size_t wtB = (size_t)CC * CC * 2;      // 2 MB per transposed weight
  const size_t qB  = M * CC * 2;               // 16.78 MB per Q/K/V tensor
  const size_t need = 4 * wtB + 3 * qB;        // 58,720,256 B

  if (ws_size < need) return;

  char* ws = (char*)d_ws;
  u16* wt_all = (u16*)ws;
  u16* Qb     = (u16*)(ws + 4 * wtB);
  u16* Kb     = Qb + M * CC;
  u16* Vb     = Kb + M * CC;
  // xb (bf16 x) lives in d_out's first half; gemm_out fully overwrites d_out.
  u16* xb     = (u16*)d_out;

  // 1) x -> bf16 into d_out scratch
  conv_f2bf<<<dim3(4096), dim3(256), 0, stream>>>(x, xb);

  // 2) transpose-convert the 4 weights
  transw<<<dim3(32, 32, 4), dim3(32, 8), 0, stream>>>(wq, wk, wv, wo, wt_all);

  // 3) QKV projections (BK=64, swizzled LDS) -> [B,H,T,D]; Q pre-scaled by SL2E
  gemm_qkv<<<dim3(CC / 128, M / 128, 3), dim3(256), 0, stream>>>(
      xb, wt_all, bq, bk, bv, Qb, Kb, Vb);

  // 4) causal attention v12b (round-20 best)
  attn_kernel<<<dim3(4 * HH, 16), dim3(256), 0, stream>>>(Qb, Kb, Vb);

  // 5) output projection (BK=64, swizzled LDS) -> d_out (FP32)
  gemm_out<<<dim3(CC / 128, M / 128, 1), dim3(256), 0, stream>>>(
      Qb, wt_all + 3 * (size_t)CC * CC, bo, (float*)d_out);
}

// Round 23
// 171.798 us; speedup vs baseline: 1.4826x; 1.0309x over previous
//
#include <hip/hip_runtime.h>
#include <hip/hip_bf16.h>
#include <type_traits>

// ---------------- types & helpers ----------------
typedef unsigned short u16;
typedef __attribute__((ext_vector_type(8))) short bf16x8;   // 8 bf16 in 4 VGPRs
typedef __attribute__((ext_vector_type(4))) float f32x4;

#define AS1 __attribute__((address_space(1)))
#define AS3 __attribute__((address_space(3)))

__device__ __forceinline__ u16 f2bf(float x) {
  unsigned u = __float_as_uint(x);
  u += 0x7fffu + ((u >> 16) & 1u);   // round-to-nearest-even
  return (u16)(u >> 16);
}

// B=4, T=2048, C=1024, H=16, D=64
#define TT 2048
#define CC 1024
#define HH 16
#define DD 64

// scale * log2(e), folded into Q at the QKV epilogue
#define SL2E 0.1803368801111137f

// ---------------- fp32 -> bf16 convert (x), vectorized 8/thread ----------------
__global__ __launch_bounds__(256) void conv_f2bf(const float* __restrict__ in,
                                                 u16* __restrict__ out) {
  int i = blockIdx.x * 256 + threadIdx.x;
  const float4* p = (const float4*)in;
  float4 f0 = p[i * 2];
  float4 f1 = p[i * 2 + 1];
  u16 vv[8] = {f2bf(f0.x), f2bf(f0.y), f2bf(f0.z), f2bf(f0.w),
               f2bf(f1.x), f2bf(f1.y), f2bf(f1.z), f2bf(f1.w)};
  ((uint4*)out)[i] = *(const uint4*)vv;
}

// ---------------- weight transpose+convert: wt[n][k] = bf(w[k][n]) ----------------
__global__ __launch_bounds__(256) void transw(const float* __restrict__ w0,
                                              const float* __restrict__ w1,
                                              const float* __restrict__ w2,
                                              const float* __restrict__ w3,
                                              u16* __restrict__ wt_all) {
  __shared__ __align__(16) u16 tile[32][33];
  const float* w = blockIdx.z == 0 ? w0 : blockIdx.z == 1 ? w1 : blockIdx.z == 2 ? w2 : w3;
  u16* wt = wt_all + (size_t)blockIdx.z * (CC * CC);
  int k0 = blockIdx.y * 32, n0 = blockIdx.x * 32;
  int tx = threadIdx.x, ty = threadIdx.y;
#pragma unroll
  for (int i = 0; i < 4; ++i) {
    int r = ty + i * 8;
    tile[r][tx] = f2bf(w[(size_t)(k0 + r) * CC + n0 + tx]);
  }
  __syncthreads();
#pragma unroll
  for (int i = 0; i < 4; ++i) {
    int r = ty + i * 8;
    wt[(size_t)(n0 + r) * CC + k0 + tx] = tile[tx][r];
  }
}

// ---------------- GEMM bodies, BK=64 (32 MFMA per barrier pair) ----------------
// LDS rows are 128B -> XOR-swizzled on 16B slots: phys = logical ^ (row&7),
// applied on BOTH the gload_lds SOURCE column and the fragment reads (G21).

// QKV GEMM: A = xb bf16, B = wt bf16 -> [B,H,T,D]; Q pre-scaled by SL2E.
__global__ __launch_bounds__(256) void gemm_qkv(const u16* __restrict__ Xb,
                                                const u16* __restrict__ wt_all,
                                                const float* __restrict__ bq,
                                                const float* __restrict__ bk,
                                                const float* __restrict__ bv,
                                                u16* __restrict__ Qb,
                                                u16* __restrict__ Kb,
                                                u16* __restrict__ Vb) {
  __shared__ __align__(16) u16 As[128 * 64];
  __shared__ __align__(16) u16 Bs[128 * 64];
  const int z = blockIdx.z;
  const u16* Bt = wt_all + (size_t)z * (CC * CC);
  const float* bias = z == 0 ? bq : z == 1 ? bk : bv;
  u16* dst = z == 0 ? Qb : z == 1 ? Kb : Vb;
  const float oscale = (z == 0) ? SL2E : 1.0f;

  const int tid = threadIdx.x;
  const int l = tid & 63, w = tid >> 6;
  const int m0 = blockIdx.y * 128, n0 = blockIdx.x * 128;
  const int mw = (w >> 1) * 64, nw = (w & 1) * 64;

  auto stage = [&](int kt) {
    int kk = kt * 64;
#pragma unroll
    for (int it = 0; it < 4; ++it) {
      int c = tid + it * 256;                 // 1024 chunks of 16B per tile
      int row = c >> 3, s = c & 7;
      int g = s ^ (row & 7);                  // inverse-swizzled source column
      __builtin_amdgcn_global_load_lds(
          (const AS1 void*)(Bt + (size_t)(n0 + row) * CC + kk + g * 8),
          (AS3 void*)(Bs + c * 8), 16, 0, 0);
      __builtin_amdgcn_global_load_lds(
          (const AS1 void*)(Xb + (size_t)(m0 + row) * CC + kk + g * 8),
          (AS3 void*)(As + c * 8), 16, 0, 0);
    }
  };

  f32x4 acc[4][4] = {};
  stage(0);
  const int KT = CC >> 6;                     // 16 K-steps
  for (int kt = 0; kt < KT; ++kt) {
    __syncthreads();
#pragma unroll
    for (int half = 0; half < 2; ++half) {
      bf16x8 a[4], b[4];
#pragma unroll
      for (int i = 0; i < 4; ++i) {
        int ra = mw + i * 16 + (l & 15);
        int sa = (half * 4 + (l >> 4)) ^ (ra & 7);
        a[i] = *(const bf16x8*)(As + ra * 64 + sa * 8);
        int rb = nw + i * 16 + (l & 15);
        int sb = (half * 4 + (l >> 4)) ^ (rb & 7);
        b[i] = *(const bf16x8*)(Bs + rb * 64 + sb * 8);
      }
#pragma unroll
      for (int i = 0; i < 4; ++i)
#pragma unroll
        for (int j = 0; j < 4; ++j)
          acc[i][j] = __builtin_amdgcn_mfma_f32_16x16x32_bf16(a[i], b[j], acc[i][j], 0, 0, 0);
    }
    __syncthreads();
    if (kt + 1 < KT) stage(kt + 1);
  }

#pragma unroll
  for (int i = 0; i < 4; ++i) {
    int rowb = m0 + mw + i * 16 + ((l >> 4) << 2);
#pragma unroll
    for (int j = 0; j < 4; ++j) {
      int col = n0 + nw + j * 16 + (l & 15);
      float bv_ = bias[col];
      int h = col >> 6, d = col & 63;
#pragma unroll
      for (int r = 0; r < 4; ++r) {
        int row = rowb + r;
        int bb = row >> 11, t = row & (TT - 1);
        dst[(((size_t)(bb * HH + h)) * TT + t) * DD + d] = f2bf((acc[i][j][r] + bv_) * oscale);
      }
    }
  }
}

// OUT GEMM: A = O in [B,H,T,D] bf16 (gathered), B = wo^T; fp32 out.
__global__ __launch_bounds__(256) void gemm_out(const u16* __restrict__ Oh,
                                                const u16* __restrict__ Bt,
                                                const float* __restrict__ bias,
                                                float* __restrict__ dst) {
  __shared__ __align__(16) u16 As[128 * 64];
  __shared__ __align__(16) u16 Bs[128 * 64];
  const int tid = threadIdx.x;
  const int l = tid & 63, w = tid >> 6;
  const int m0 = blockIdx.y * 128, n0 = blockIdx.x * 128;
  const int mw = (w >> 1) * 64, nw = (w & 1) * 64;

  auto stage = [&](int kt) {
    int kk = kt * 64;
#pragma unroll
    for (int it = 0; it < 4; ++it) {
      int c = tid + it * 256;
      int row = c >> 3, s = c & 7;
      int g = s ^ (row & 7);
      __builtin_amdgcn_global_load_lds(
          (const AS1 void*)(Bt + (size_t)(n0 + row) * CC + kk + g * 8),
          (AS3 void*)(Bs + c * 8), 16, 0, 0);
      // A gather from [B,H,T,D]: k = h*64+d; 8-chunks never cross head boundary
      int gr = m0 + row, gk = kk + g * 8;
      int bb = gr >> 11, t = gr & (TT - 1);
      int h = gk >> 6, d = gk & 63;
      __builtin_amdgcn_global_load_lds(
          (const AS1 void*)(Oh + (((size_t)(bb * HH + h)) * TT + t) * DD + d),
          (AS3 void*)(As + c * 8), 16, 0, 0);
    }
  };

  f32x4 acc[4][4] = {};
  stage(0);
  const int KT = CC >> 6;
  for (int kt = 0; kt < KT; ++kt) {
    __syncthreads();
#pragma unroll
    for (int half = 0; half < 2; ++half) {
      bf16x8 a[4], b[4];
#pragma unroll
      for (int i = 0; i < 4; ++i) {
        int ra = mw + i * 16 + (l & 15);
        int sa = (half * 4 + (l >> 4)) ^ (ra & 7);
        a[i] = *(const bf16x8*)(As + ra * 64 + sa * 8);
        int rb = nw + i * 16 + (l & 15);
        int sb = (half * 4 + (l >> 4)) ^ (rb & 7);
        b[i] = *(const bf16x8*)(Bs + rb * 64 + sb * 8);
      }
#pragma unroll
      for (int i = 0; i < 4; ++i)
#pragma unroll
        for (int j = 0; j < 4; ++j)
          acc[i][j] = __builtin_amdgcn_mfma_f32_16x16x32_bf16(a[i], b[j], acc[i][j], 0, 0, 0);
    }
    __syncthreads();
    if (kt + 1 < KT) stage(kt + 1);
  }

#pragma unroll
  for (int i = 0; i < 4; ++i) {
    int rowb = m0 + mw + i * 16 + ((l >> 4) << 2);
#pragma unroll
    for (int j = 0; j < 4; ++j) {
      int col = n0 + nw + j * 16 + (l & 15);
      float bv_ = bias[col];
#pragma unroll
      for (int r = 0; r < 4; ++r)
        dst[(size_t)(rowb + r) * CC + col] = acc[i][j][r] + bv_;
    }
  }
}

// ---------------- causal flash attention v12c ----------------
// Round-20 best (79.5 us) + T5 s_setprio(1) around the QK^T and PV MFMA
// clusters. Mechanism gate satisfied: 5 blocks/CU x 4 waves at independent
// phases (blocks not cross-synced) -> scheduler can favor MFMA-issuing waves
// (m191: +4-7% attn in this regime; null only for lockstep GEMM waves).
__global__ __launch_bounds__(256, 3) void attn_kernel(u16* __restrict__ Q,
                                                      const u16* __restrict__ K,
                                                      const u16* __restrict__ V) {
  __shared__ __align__(16) u16 Ks[64 * 64];      // [key][d], swizzled
  __shared__ __align__(16) u16 Vt[64 * 64];      // [d][key], swizzled
  __shared__ __align__(16) u16 Ps[4][32 * 64];   // per-wave P (32 rows), swizzled

  const int tid = threadIdx.x;
  const int l = tid & 63, w = tid >> 6;          // 4 waves
  const int bh = blockIdx.x;                      // 0..63  (XCD = bh%8)
  const int qt = blockIdx.y;                      // 0..15, heavy-first
  const size_t base = (size_t)bh * TT * DD;
  const int kp = tid & 31;                        // V-stage: key pair
  const int dgr = tid >> 5;                       // V-stage: d-group of 8 (0..7)

  const int q0 = TT - 128 - qt * 128;             // qt=0 -> heaviest (nch=32)
  const int nch = (q0 >> 6) + 2;                  // >= 4
  const int wrow0 = q0 + w * 32;

  bf16x8 vones;
#pragma unroll
  for (int j = 0; j < 8; ++j) vones[j] = (short)0x3F80;

  auto stageK = [&](int k0) {
#pragma unroll
    for (int it = 0; it < 2; ++it) {
      int c = tid + it * 256;                     // 512 chunks of 16B
      int row = c >> 3, s = c & 7;
      int g = s ^ (row & 7);
      __builtin_amdgcn_global_load_lds(
          (const AS1 void*)(K + base + (size_t)(k0 + row) * DD + g * 8),
          (AS3 void*)(Ks + c * 8), 16, 0, 0);
    }
  };
  auto loadV = [&](int k0, uint4& a0, uint4& a1) {
    const u16* vp = V + base + (size_t)(k0 + 2 * kp) * DD + dgr * 8;
    a0 = *(const uint4*)vp;
    a1 = *(const uint4*)(vp + DD);
  };
  auto writeV = [&](uint4 a0, uint4 a1) {
    u16 v0[8], v1[8];
    *(uint4*)v0 = a0; *(uint4*)v1 = a1;
#pragma unroll
    for (int j = 0; j < 8; ++j) {
      int d = dgr * 8 + j;
      unsigned pk = (unsigned)v0[j] | ((unsigned)v1[j] << 16);
      int addr = d * 64 + (((kp >> 2) ^ (d & 7)) << 3) + ((kp & 3) << 1);
      *(unsigned*)(Vt + addr) = pk;
    }
  };

  // Q fragments: 2 row-tiles per wave (rows wrow0..wrow0+31), Q pre-scaled
  bf16x8 qa[2][2];
#pragma unroll
  for (int mt = 0; mt < 2; ++mt) {
    const u16* qp = Q + base + (size_t)(wrow0 + mt * 16 + (l & 15)) * DD + (l >> 4) * 8;
    qa[mt][0] = *(const bf16x8*)(qp);
    qa[mt][1] = *(const bf16x8*)(qp + 32);
  }

  f32x4 oacc[2][5] = {};                          // [mt][0..3]=O, [mt][4]=rowsum

  // body: all LDS addresses loop-invariant (single buffer); masked compile-time
  auto body = [&](auto maskedC, int k0) {
    constexpr bool masked = decltype(maskedC)::value;
    bool act0 = true, act1 = true;
    if (masked) {
      act1 = (k0 <= wrow0 + 31);
      act0 = (k0 <= wrow0 + 15);
      if (!act1) return;                          // act0 implies act1
    }
    const bool need_mask = masked && (k0 + 63 > wrow0);

    // --- S = Q K^T (up to 32 q-rows x 64 k) ---
    f32x4 sa[2][4];
    __builtin_amdgcn_s_setprio(1);                // T5: favor MFMA cluster
#pragma unroll
    for (int nt = 0; nt < 4; ++nt) {
      int krow = nt * 16 + (l & 15);
      int rb = krow & 7;
      bf16x8 kb0 = *(const bf16x8*)(Ks + krow * 64 + (((l >> 4) ^ rb) << 3));
      bf16x8 kb1 = *(const bf16x8*)(Ks + krow * 64 + ((((l >> 4) + 4) ^ rb) << 3));
#pragma unroll
      for (int mt = 0; mt < 2; ++mt) {
        if (!masked || (mt ? act1 : act0)) {
          f32x4 zz = {};
          zz = __builtin_amdgcn_mfma_f32_16x16x32_bf16(qa[mt][0], kb0, zz, 0, 0, 0);
          zz = __builtin_amdgcn_mfma_f32_16x16x32_bf16(qa[mt][1], kb1, zz, 0, 0, 0);
          sa[mt][nt] = zz;
        }
      }
    }
    __builtin_amdgcn_s_setprio(0);

    // --- softmax numerators: p = exp2(s); trunc bf16 store ---
#pragma unroll
    for (int mt = 0; mt < 2; ++mt) {
      if (!masked || (mt ? act1 : act0)) {
#pragma unroll
        for (int r = 0; r < 4; ++r) {
          int lrow = mt * 16 + ((l >> 4) << 2) + r;   // 0..31
          int row = wrow0 + lrow;
#pragma unroll
          for (int nt = 0; nt < 4; ++nt) {
            float p = exp2f(sa[mt][nt][r]);
            if (masked) {
              if (need_mask) {
                int col = k0 + nt * 16 + (l & 15);
                if (col > row) p = 0.f;
              }
            }
            int slot = ((2 * nt + ((l & 15) >> 3)) & 7) ^ (lrow & 7);
            Ps[w][lrow * 64 + (slot << 3) + (l & 7)] =
                (u16)(__float_as_uint(p) >> 16);      // trunc; cancels num/denom
          }
        }
      }
    }

    // --- O += P @ V; dt=4 uses reg-ones -> rowsum ---
    bf16x8 pa[2][2];
#pragma unroll
    for (int mt = 0; mt < 2; ++mt) {
      if (!masked || (mt ? act1 : act0)) {
        int arow = mt * 16 + (l & 15), ab = arow & 7;
        pa[mt][0] = *(const bf16x8*)(&Ps[w][arow * 64 + (((l >> 4) ^ ab) << 3)]);
        pa[mt][1] = *(const bf16x8*)(&Ps[w][arow * 64 + ((((l >> 4) + 4) ^ ab) << 3)]);
      }
    }
    __builtin_amdgcn_s_setprio(1);                // T5: favor MFMA cluster
#pragma unroll
    for (int dt = 0; dt < 5; ++dt) {
      bf16x8 vb0, vb1;
      if (dt < 4) {
        int vrow = dt * 16 + (l & 15), vb = vrow & 7;
        vb0 = *(const bf16x8*)(Vt + vrow * 64 + (((l >> 4) ^ vb) << 3));
        vb1 = *(const bf16x8*)(Vt + vrow * 64 + ((((l >> 4) + 4) ^ vb) << 3));
      } else {
        vb0 = vones; vb1 = vones;
      }
#pragma unroll
      for (int mt = 0; mt < 2; ++mt) {
        if (!masked || (mt ? act1 : act0)) {
          oacc[mt][dt] = __builtin_amdgcn_mfma_f32_16x16x32_bf16(pa[mt][0], vb0, oacc[mt][dt], 0, 0, 0);
          oacc[mt][dt] = __builtin_amdgcn_mfma_f32_16x16x32_bf16(pa[mt][1], vb1, oacc[mt][dt], 0, 0, 0);
        }
      }
    }
    __builtin_amdgcn_s_setprio(0);
  };

  constexpr std::false_type noMask{};
  constexpr std::true_type  doMask{};

  // prologue: stage chunk 0
  {
    uint4 a0, a1;
    stageK(0);
    loadV(0, a0, a1);
    writeV(a0, a1);
    __syncthreads();
  }

  // unmasked chunks 0..nch-3
  for (int ch = 0; ch < nch - 2; ++ch) {
    uint4 na0, na1;
    loadV((ch + 1) * 64, na0, na1);               // issue EARLY (regs, not LDS)
    body(noMask, ch * 64);
    __syncthreads();                              // Ks/Vt free
    stageK((ch + 1) * 64);
    writeV(na0, na1);
    __syncthreads();                              // next chunk published
  }
  // masked chunk nch-2 (stages nch-1 after), then masked chunk nch-1
  {
    uint4 na0, na1;
    loadV((nch - 1) * 64, na0, na1);
    body(doMask, (nch - 2) * 64);
    __syncthreads();
    stageK((nch - 1) * 64);
    writeV(na0, na1);
    __syncthreads();
  }
  body(doMask, (nch - 1) * 64);

  // --- normalize + write O over Q (rows owned by this block only) ---
#pragma unroll
  for (int mt = 0; mt < 2; ++mt) {
#pragma unroll
    for (int r = 0; r < 4; ++r) {
      float inv = 1.f / oacc[mt][4][r];
      int t = wrow0 + mt * 16 + ((l >> 4) << 2) + r;
#pragma unroll
      for (int dt = 0; dt < 4; ++dt)
        Q[base + (size_t)t * DD + dt * 16 + (l & 15)] = f2bf(oacc[mt][dt][r] * inv);
    }
  }
}

// ---------------- launcher ----------------
extern "C" void kernel_launch(void* const* d_in, const int* in_sizes, int n_in,
                              void* d_out, int out_size, void* d_ws, size_t ws_size,
                              hipStream_t stream) {
  const float* x  = (const float*)d_in[0];
  const float* wq = (const float*)d_in[1];
  const float* bq = (const float*)d_in[2];
  const float* wk = (const float*)d_in[3];
  const float* bk = (const float*)d_in[4];
  const float* wv = (const float*)d_in[5];
  const float* bv = (const float*)d_in[6];
  const float* wo = (const float*)d_in[7];
  const float* bo = (const float*)d_in[8];

  const size_t M   = 4 * (size_t)TT;           // 8192
  const size_t wtB = (size_t)CC * CC * 2;      // 2 MB per transposed weight
  const size_t qB  = M * CC * 2;               // 16.78 MB per Q/K/V tensor
  const size_t need = 4 * wtB + 3 * qB;        // 58,720,256 B

  if (ws_size < need) return;

  char* ws = (char*)d_ws;
  u16* wt_all = (u16*)ws;
  u16* Qb     = (u16*)(ws + 4 * wtB);
  u16* Kb     = Qb + M * CC;
  u16* Vb     = Kb + M * CC;
  // xb (bf16 x) lives in d_out's first half; gemm_out fully overwrites d_out.
  u16* xb     = (u16*)d_out;

  // 1) x -> bf16 into d_out scratch
  conv_f2bf<<<dim3(4096), dim3(256), 0, stream>>>(x, xb);

  // 2) transpose-convert the 4 weights
  transw<<<dim3(32, 32, 4), dim3(32, 8), 0, stream>>>(wq, wk, wv, wo, wt_all);

  // 3) QKV projections (BK=64, swizzled LDS) -> [B,H,T,D]; Q pre-scaled by SL2E
  gemm_qkv<<<dim3(CC / 128, M / 128, 3), dim3(256), 0, stream>>>(
      xb, wt_all, bq, bk, bv, Qb, Kb, Vb);

  // 4) causal attention v12c (round-20 best + T5 setprio on MFMA clusters)
  attn_kernel<<<dim3(4 * HH, 16), dim3(256), 0, stream>>>(Qb, Kb, Vb);

  // 5) output projection (BK=64, swizzled LDS) -> d_out (FP32)
  gemm_out<<<dim3(CC / 128, M / 128, 1), dim3(256), 0, stream>>>(
      Qb, wt_all + 3 * (size_t)CC * CC, bo, (float*)d_out);
}

// Round 24
// 170.312 us; speedup vs baseline: 1.4955x; 1.0087x over previous
//
#include <hip/hip_runtime.h>
#include <hip/hip_bf16.h>
#include <type_traits>

// ---------------- types & helpers ----------------
typedef unsigned short u16;
typedef __attribute__((ext_vector_type(8))) short bf16x8;   // 8 bf16 in 4 VGPRs
typedef __attribute__((ext_vector_type(4))) float f32x4;

#define AS1 __attribute__((address_space(1)))
#define AS3 __attribute__((address_space(3)))

__device__ __forceinline__ u16 f2bf(float x) {
  unsigned u = __float_as_uint(x);
  u += 0x7fffu + ((u >> 16) & 1u);   // round-to-nearest-even
  return (u16)(u >> 16);
}

// B=4, T=2048, C=1024, H=16, D=64
#define TT 2048
#define CC 1024
#define HH 16
#define DD 64

// scale * log2(e), folded into Q at the QKV epilogue
#define SL2E 0.1803368801111137f

// ---------------- fused pre-pass: x->bf16 convert  ||  weight transpose+convert ----------------
// Blocks 0..4095: conv (xb[i] = bf(x[i]), 8 elem/thread).
// Blocks 4096..8191: transw (wt[n][k] = bf(w[k][n]), one 32x32 tile each).
// The two halves are data-independent; merging overlaps their execution and
// saves one kernel launch.
__global__ __launch_bounds__(256) void prep(const float* __restrict__ x,
                                            u16* __restrict__ xb,
                                            const float* __restrict__ w0,
                                            const float* __restrict__ w1,
                                            const float* __restrict__ w2,
                                            const float* __restrict__ w3,
                                            u16* __restrict__ wt_all) {
  const int bid = blockIdx.x;
  if (bid < 4096) {
    int i = bid * 256 + threadIdx.x;
    const float4* p = (const float4*)x;
    float4 f0 = p[i * 2];
    float4 f1 = p[i * 2 + 1];
    u16 vv[8] = {f2bf(f0.x), f2bf(f0.y), f2bf(f0.z), f2bf(f0.w),
                 f2bf(f1.x), f2bf(f1.y), f2bf(f1.z), f2bf(f1.w)};
    ((uint4*)xb)[i] = *(const uint4*)vv;
  } else {
    __shared__ __align__(16) u16 tile[32][33];
    int b = bid - 4096;                       // 0..4095 = z*1024 + ky*32 + nx
    int z = b >> 10;
    int ky = (b >> 5) & 31;
    int nx = b & 31;
    const float* w = z == 0 ? w0 : z == 1 ? w1 : z == 2 ? w2 : w3;
    u16* wt = wt_all + (size_t)z * (CC * CC);
    int k0 = ky * 32, n0 = nx * 32;
    int tx = threadIdx.x & 31, ty = threadIdx.x >> 5;   // 32 x 8
#pragma unroll
    for (int i = 0; i < 4; ++i) {
      int r = ty + i * 8;
      tile[r][tx] = f2bf(w[(size_t)(k0 + r) * CC + n0 + tx]);
    }
    __syncthreads();
#pragma unroll
    for (int i = 0; i < 4; ++i) {
      int r = ty + i * 8;
      wt[(size_t)(n0 + r) * CC + k0 + tx] = tile[tx][r];
    }
  }
}

// ---------------- GEMM bodies, BK=64 (32 MFMA per barrier pair) ----------------
// LDS rows are 128B -> XOR-swizzled on 16B slots: phys = logical ^ (row&7),
// applied on BOTH the gload_lds SOURCE column and the fragment reads (G21).

// QKV GEMM: A = xb bf16, B = wt bf16 -> [B,H,T,D]; Q pre-scaled by SL2E.
__global__ __launch_bounds__(256) void gemm_qkv(const u16* __restrict__ Xb,
                                                const u16* __restrict__ wt_all,
                                                const float* __restrict__ bq,
                                                const float* __restrict__ bk,
                                                const float* __restrict__ bv,
                                                u16* __restrict__ Qb,
                                                u16* __restrict__ Kb,
                                                u16* __restrict__ Vb) {
  __shared__ __align__(16) u16 As[128 * 64];
  __shared__ __align__(16) u16 Bs[128 * 64];
  const int z = blockIdx.z;
  const u16* Bt = wt_all + (size_t)z * (CC * CC);
  const float* bias = z == 0 ? bq : z == 1 ? bk : bv;
  u16* dst = z == 0 ? Qb : z == 1 ? Kb : Vb;
  const float oscale = (z == 0) ? SL2E : 1.0f;

  const int tid = threadIdx.x;
  const int l = tid & 63, w = tid >> 6;
  const int m0 = blockIdx.y * 128, n0 = blockIdx.x * 128;
  const int mw = (w >> 1) * 64, nw = (w & 1) * 64;

  auto stage = [&](int kt) {
    int kk = kt * 64;
#pragma unroll
    for (int it = 0; it < 4; ++it) {
      int c = tid + it * 256;                 // 1024 chunks of 16B per tile
      int row = c >> 3, s = c & 7;
      int g = s ^ (row & 7);                  // inverse-swizzled source column
      __builtin_amdgcn_global_load_lds(
          (const AS1 void*)(Bt + (size_t)(n0 + row) * CC + kk + g * 8),
          (AS3 void*)(Bs + c * 8), 16, 0, 0);
      __builtin_amdgcn_global_load_lds(
          (const AS1 void*)(Xb + (size_t)(m0 + row) * CC + kk + g * 8),
          (AS3 void*)(As + c * 8), 16, 0, 0);
    }
  };

  f32x4 acc[4][4] = {};
  stage(0);
  const int KT = CC >> 6;                     // 16 K-steps
  for (int kt = 0; kt < KT; ++kt) {
    __syncthreads();
#pragma unroll
    for (int half = 0; half < 2; ++half) {
      bf16x8 a[4], b[4];
#pragma unroll
      for (int i = 0; i < 4; ++i) {
        int ra = mw + i * 16 + (l & 15);
        int sa = (half * 4 + (l >> 4)) ^ (ra & 7);
        a[i] = *(const bf16x8*)(As + ra * 64 + sa * 8);
        int rb = nw + i * 16 + (l & 15);
        int sb = (half * 4 + (l >> 4)) ^ (rb & 7);
        b[i] = *(const bf16x8*)(Bs + rb * 64 + sb * 8);
      }
#pragma unroll
      for (int i = 0; i < 4; ++i)
#pragma unroll
        for (int j = 0; j < 4; ++j)
          acc[i][j] = __builtin_amdgcn_mfma_f32_16x16x32_bf16(a[i], b[j], acc[i][j], 0, 0, 0);
    }
    __syncthreads();
    if (kt + 1 < KT) stage(kt + 1);
  }

#pragma unroll
  for (int i = 0; i < 4; ++i) {
    int rowb = m0 + mw + i * 16 + ((l >> 4) << 2);
#pragma unroll
    for (int j = 0; j < 4; ++j) {
      int col = n0 + nw + j * 16 + (l & 15);
      float bv_ = bias[col];
      int h = col >> 6, d = col & 63;
#pragma unroll
      for (int r = 0; r < 4; ++r) {
        int row = rowb + r;
        int bb = row >> 11, t = row & (TT - 1);
        dst[(((size_t)(bb * HH + h)) * TT + t) * DD + d] = f2bf((acc[i][j][r] + bv_) * oscale);
      }
    }
  }
}

// OUT GEMM: A = O in [B,H,T,D] bf16 (gathered), B = wo^T; fp32 out.
__global__ __launch_bounds__(256) void gemm_out(const u16* __restrict__ Oh,
                                                const u16* __restrict__ Bt,
                                                const float* __restrict__ bias,
                                                float* __restrict__ dst) {
  __shared__ __align__(16) u16 As[128 * 64];
  __shared__ __align__(16) u16 Bs[128 * 64];
  const int tid = threadIdx.x;
  const int l = tid & 63, w = tid >> 6;
  const int m0 = blockIdx.y * 128, n0 = blockIdx.x * 128;
  const int mw = (w >> 1) * 64, nw = (w & 1) * 64;

  auto stage = [&](int kt) {
    int kk = kt * 64;
#pragma unroll
    for (int it = 0; it < 4; ++it) {
      int c = tid + it * 256;
      int row = c >> 3, s = c & 7;
      int g = s ^ (row & 7);
      __builtin_amdgcn_global_load_lds(
          (const AS1 void*)(Bt + (size_t)(n0 + row) * CC + kk + g * 8),
          (AS3 void*)(Bs + c * 8), 16, 0, 0);
      // A gather from [B,H,T,D]: k = h*64+d; 8-chunks never cross head boundary
      int gr = m0 + row, gk = kk + g * 8;
      int bb = gr >> 11, t = gr & (TT - 1);
      int h = gk >> 6, d = gk & 63;
      __builtin_amdgcn_global_load_lds(
          (const AS1 void*)(Oh + (((size_t)(bb * HH + h)) * TT + t) * DD + d),
          (AS3 void*)(As + c * 8), 16, 0, 0);
    }
  };

  f32x4 acc[4][4] = {};
  stage(0);
  const int KT = CC >> 6;
  for (int kt = 0; kt < KT; ++kt) {
    __syncthreads();
#pragma unroll
    for (int half = 0; half < 2; ++half) {
      bf16x8 a[4], b[4];
#pragma unroll
      for (int i = 0; i < 4; ++i) {
        int ra = mw + i * 16 + (l & 15);
        int sa = (half * 4 + (l >> 4)) ^ (ra & 7);
        a[i] = *(const bf16x8*)(As + ra * 64 + sa * 8);
        int rb = nw + i * 16 + (l & 15);
        int sb = (half * 4 + (l >> 4)) ^ (rb & 7);
        b[i] = *(const bf16x8*)(Bs + rb * 64 + sb * 8);
      }
#pragma unroll
      for (int i = 0; i < 4; ++i)
#pragma unroll
        for (int j = 0; j < 4; ++j)
          acc[i][j] = __builtin_amdgcn_mfma_f32_16x16x32_bf16(a[i], b[j], acc[i][j], 0, 0, 0);
    }
    __syncthreads();
    if (kt + 1 < KT) stage(kt + 1);
  }

#pragma unroll
  for (int i = 0; i < 4; ++i) {
    int rowb = m0 + mw + i * 16 + ((l >> 4) << 2);
#pragma unroll
    for (int j = 0; j < 4; ++j) {
      int col = n0 + nw + j * 16 + (l & 15);
      float bv_ = bias[col];
#pragma unroll
      for (int r = 0; r < 4; ++r)
        dst[(size_t)(rowb + r) * CC + col] = acc[i][j][r] + bv_;
    }
  }
}

// ---------------- causal flash attention v12c (round-23 best: 73.7 us) ----------------
// 32 rows/wave x 4 waves, single-buffer 32KB LDS (5 blocks/CU), heavy-first grid,
// XCD=bh%8, trunc Ps store, reg-ones rowsum, T5 setprio on MFMA clusters,
// (256,3) = verified no-spill bound (VGPR 84).
__global__ __launch_bounds__(256, 3) void attn_kernel(u16* __restrict__ Q,
                                                      const u16* __restrict__ K,
                                                      const u16* __restrict__ V) {
  __shared__ __align__(16) u16 Ks[64 * 64];      // [key][d], swizzled
  __shared__ __align__(16) u16 Vt[64 * 64];      // [d][key], swizzled
  __shared__ __align__(16) u16 Ps[4][32 * 64];   // per-wave P (32 rows), swizzled

  const int tid = threadIdx.x;
  const int l = tid & 63, w = tid >> 6;          // 4 waves
  const int bh = blockIdx.x;                      // 0..63  (XCD = bh%8)
  const int qt = blockIdx.y;                      // 0..15, heavy-first
  const size_t base = (size_t)bh * TT * DD;
  const int kp = tid & 31;                        // V-stage: key pair
  const int dgr = tid >> 5;                       // V-stage: d-group of 8 (0..7)

  const int q0 = TT - 128 - qt * 128;             // qt=0 -> heaviest (nch=32)
  const int nch = (q0 >> 6) + 2;                  // >= 4
  const int wrow0 = q0 + w * 32;

  bf16x8 vones;
#pragma unroll
  for (int j = 0; j < 8; ++j) vones[j] = (short)0x3F80;

  auto stageK = [&](int k0) {
#pragma unroll
    for (int it = 0; it < 2; ++it) {
      int c = tid + it * 256;                     // 512 chunks of 16B
      int row = c >> 3, s = c & 7;
      int g = s ^ (row & 7);
      __builtin_amdgcn_global_load_lds(
          (const AS1 void*)(K + base + (size_t)(k0 + row) * DD + g * 8),
          (AS3 void*)(Ks + c * 8), 16, 0, 0);
    }
  };
  auto loadV = [&](int k0, uint4& a0, uint4& a1) {
    const u16* vp = V + base + (size_t)(k0 + 2 * kp) * DD + dgr * 8;
    a0 = *(const uint4*)vp;
    a1 = *(const uint4*)(vp + DD);
  };
  auto writeV = [&](uint4 a0, uint4 a1) {
    u16 v0[8], v1[8];
    *(uint4*)v0 = a0; *(uint4*)v1 = a1;
#pragma unroll
    for (int j = 0; j < 8; ++j) {
      int d = dgr * 8 + j;
      unsigned pk = (unsigned)v0[j] | ((unsigned)v1[j] << 16);
      int addr = d * 64 + (((kp >> 2) ^ (d & 7)) << 3) + ((kp & 3) << 1);
      *(unsigned*)(Vt + addr) = pk;
    }
  };

  // Q fragments: 2 row-tiles per wave (rows wrow0..wrow0+31), Q pre-scaled
  bf16x8 qa[2][2];
#pragma unroll
  for (int mt = 0; mt < 2; ++mt) {
    const u16* qp = Q + base + (size_t)(wrow0 + mt * 16 + (l & 15)) * DD + (l >> 4) * 8;
    qa[mt][0] = *(const bf16x8*)(qp);
    qa[mt][1] = *(const bf16x8*)(qp + 32);
  }

  f32x4 oacc[2][5] = {};                          // [mt][0..3]=O, [mt][4]=rowsum

  // body: all LDS addresses loop-invariant (single buffer); masked compile-time
  auto body = [&](auto maskedC, int k0) {
    constexpr bool masked = decltype(maskedC)::value;
    bool act0 = true, act1 = true;
    if (masked) {
      act1 = (k0 <= wrow0 + 31);
      act0 = (k0 <= wrow0 + 15);
      if (!act1) return;                          // act0 implies act1
    }
    const bool need_mask = masked && (k0 + 63 > wrow0);

    // --- S = Q K^T (up to 32 q-rows x 64 k) ---
    f32x4 sa[2][4];
    __builtin_amdgcn_s_setprio(1);                // T5: favor MFMA cluster
#pragma unroll
    for (int nt = 0; nt < 4; ++nt) {
      int krow = nt * 16 + (l & 15);
      int rb = krow & 7;
      bf16x8 kb0 = *(const bf16x8*)(Ks + krow * 64 + (((l >> 4) ^ rb) << 3));
      bf16x8 kb1 = *(const bf16x8*)(Ks + krow * 64 + ((((l >> 4) + 4) ^ rb) << 3));
#pragma unroll
      for (int mt = 0; mt < 2; ++mt) {
        if (!masked || (mt ? act1 : act0)) {
          f32x4 zz = {};
          zz = __builtin_amdgcn_mfma_f32_16x16x32_bf16(qa[mt][0], kb0, zz, 0, 0, 0);
          zz = __builtin_amdgcn_mfma_f32_16x16x32_bf16(qa[mt][1], kb1, zz, 0, 0, 0);
          sa[mt][nt] = zz;
        }
      }
    }
    __builtin_amdgcn_s_setprio(0);

    // --- softmax numerators: p = exp2(s); trunc bf16 store ---
#pragma unroll
    for (int mt = 0; mt < 2; ++mt) {
      if (!masked || (mt ? act1 : act0)) {
#pragma unroll
        for (int r = 0; r < 4; ++r) {
          int lrow = mt * 16 + ((l >> 4) << 2) + r;   // 0..31
          int row = wrow0 + lrow;
#pragma unroll
          for (int nt = 0; nt < 4; ++nt) {
            float p = exp2f(sa[mt][nt][r]);
            if (masked) {
              if (need_mask) {
                int col = k0 + nt * 16 + (l & 15);
                if (col > row) p = 0.f;
              }
            }
            int slot = ((2 * nt + ((l & 15) >> 3)) & 7) ^ (lrow & 7);
            Ps[w][lrow * 64 + (slot << 3) + (l & 7)] =
                (u16)(__float_as_uint(p) >> 16);      // trunc; cancels num/denom
          }
        }
      }
    }

    // --- O += P @ V; dt=4 uses reg-ones -> rowsum ---
    bf16x8 pa[2][2];
#pragma unroll
    for (int mt = 0; mt < 2; ++mt) {
      if (!masked || (mt ? act1 : act0)) {
        int arow = mt * 16 + (l & 15), ab = arow & 7;
        pa[mt][0] = *(const bf16x8*)(&Ps[w][arow * 64 + (((l >> 4) ^ ab) << 3)]);
        pa[mt][1] = *(const bf16x8*)(&Ps[w][arow * 64 + ((((l >> 4) + 4) ^ ab) << 3)]);
      }
    }
    __builtin_amdgcn_s_setprio(1);                // T5: favor MFMA cluster
#pragma unroll
    for (int dt = 0; dt < 5; ++dt) {
      bf16x8 vb0, vb1;
      if (dt < 4) {
        int vrow = dt * 16 + (l & 15), vb = vrow & 7;
        vb0 = *(const bf16x8*)(Vt + vrow * 64 + (((l >> 4) ^ vb) << 3));
        vb1 = *(const bf16x8*)(Vt + vrow * 64 + ((((l >> 4) + 4) ^ vb) << 3));
      } else {
        vb0 = vones; vb1 = vones;
      }
#pragma unroll
      for (int mt = 0; mt < 2; ++mt) {
        if (!masked || (mt ? act1 : act0)) {
          oacc[mt][dt] = __builtin_amdgcn_mfma_f32_16x16x32_bf16(pa[mt][0], vb0, oacc[mt][dt], 0, 0, 0);
          oacc[mt][dt] = __builtin_amdgcn_mfma_f32_16x16x32_bf16(pa[mt][1], vb1, oacc[mt][dt], 0, 0, 0);
        }
      }
    }
    __builtin_amdgcn_s_setprio(0);
  };

  constexpr std::false_type noMask{};
  constexpr std::true_type  doMask{};

  // prologue: stage chunk 0
  {
    uint4 a0, a1;
    stageK(0);
    loadV(0, a0, a1);
    writeV(a0, a1);
    __syncthreads();
  }

  // unmasked chunks 0..nch-3
  for (int ch = 0; ch < nch - 2; ++ch) {
    uint4 na0, na1;
    loadV((ch + 1) * 64, na0, na1);               // issue EARLY (regs, not LDS)
    body(noMask, ch * 64);
    __syncthreads();                              // Ks/Vt free
    stageK((ch + 1) * 64);
    writeV(na0, na1);
    __syncthreads();                              // next chunk published
  }
  // masked chunk nch-2 (stages nch-1 after), then masked chunk nch-1
  {
    uint4 na0, na1;
    loadV((nch - 1) * 64, na0, na1);
    body(doMask, (nch - 2) * 64);
    __syncthreads();
    stageK((nch - 1) * 64);
    writeV(na0, na1);
    __syncthreads();
  }
  body(doMask, (nch - 1) * 64);

  // --- normalize + write O over Q (rows owned by this block only) ---
#pragma unroll
  for (int mt = 0; mt < 2; ++mt) {
#pragma unroll
    for (int r = 0; r < 4; ++r) {
      float inv = 1.f / oacc[mt][4][r];
      int t = wrow0 + mt * 16 + ((l >> 4) << 2) + r;
#pragma unroll
      for (int dt = 0; dt < 4; ++dt)
        Q[base + (size_t)t * DD + dt * 16 + (l & 15)] = f2bf(oacc[mt][dt][r] * inv);
    }
  }
}

// ---------------- launcher ----------------
extern "C" void kernel_launch(void* const* d_in, const int* in_sizes, int n_in,
                              void* d_out, int out_size, void* d_ws, size_t ws_size,
                              hipStream_t stream) {
  const float* x  = (const float*)d_in[0];
  const float* wq = (const float*)d_in[1];
  const float* bq = (const float*)d_in[2];
  const float* wk = (const float*)d_in[3];
  const float* bk = (const float*)d_in[4];
  const float* wv = (const float*)d_in[5];
  const float* bv = (const float*)d_in[6];
  const float* wo = (const float*)d_in[7];
  const float* bo = (const float*)d_in[8];

  const size_t M   = 4 * (size_t)TT;           // 8192
  const size_t wtB = (size_t)CC * CC * 2;      // 2 MB per transposed weight
  const size_t qB  = M * CC * 2;               // 16.78 MB per Q/K/V tensor
  const size_t need = 4 * wtB + 3 * qB;        // 58,720,256 B

  if (ws_size < need) return;

  char* ws = (char*)d_ws;
  u16* wt_all = (u16*)ws;
  u16* Qb     = (u16*)(ws + 4 * wtB);
  u16* Kb     = Qb + M * CC;
  u16* Vb     = Kb + M * CC;
  // xb (bf16 x) lives in d_out's first half; gemm_out fully overwrites d_out.
  u16* xb     = (u16*)d_out;

  // 1) fused pre-pass: x->bf16 (blocks 0..4095) || weight transpose (4096..8191)
  prep<<<dim3(8192), dim3(256), 0, stream>>>(x, xb, wq, wk, wv, wo, wt_all);

  // 2) QKV projections (BK=64, swizzled LDS) -> [B,H,T,D]; Q pre-scaled by SL2E
  gemm_qkv<<<dim3(CC / 128, M / 128, 3), dim3(256), 0, stream>>>(
      xb, wt_all, bq, bk, bv, Qb, Kb, Vb);

  // 3) causal attention v12c (round-23 best)
  attn_kernel<<<dim3(4 * HH, 16), dim3(256), 0, stream>>>(Qb, Kb, Vb);

  // 4) output projection (BK=64, swizzled LDS) -> d_out (FP32)
  gemm_out<<<dim3(CC / 128, M / 128, 1), dim3(256), 0, stream>>>(
      Qb, wt_all + 3 * (size_t)CC * CC, bo, (float*)d_out);
}